// Round 13
// baseline (143.852 us; speedup 1.0000x reference)
//
#include <hip/hip_runtime.h>

#define NEG_SLOPE 0.2f
#define LOG2E 1.44269504088896340736f

#define BUK_SHIFT 7
#define BUK_NODES 128
#define BUK_CAP   5120
#define MAX_NBUK  512
#define OVER_CAP  4096
#define CSR_MAXR  20        // ceil(BUK_CAP/256)

typedef __attribute__((ext_vector_type(8))) short short8v;
typedef __attribute__((ext_vector_type(4))) float float4v;

__device__ __forceinline__ float bf2f(unsigned short u) {
    union { unsigned int u32; float f; } c;
    c.u32 = ((unsigned int)u) << 16;
    return c.f;
}
__device__ __forceinline__ unsigned short f2bf(float f) {
    union { float f; unsigned int u32; } c; c.f = f;
    unsigned int b = c.u32;
    b += 0x7fffu + ((b >> 16) & 1u);   // round-to-nearest-even
    return (unsigned short)(b >> 16);
}
// unsigned byte b of dword d -> float (v_cvt_f32_ubyteN, 1 instr)
__device__ __forceinline__ float ub2f(unsigned int d, int b) {
    return (float)((d >> (8 * b)) & 0xffu);
}

// ---------------------------------------------------------------------------
// K0: fused init. Blocks 0..31: W -> bf16 in MFMA B-fragment order.
// Block 32: zero bucket counters + overflow counter.
// ---------------------------------------------------------------------------
__global__ __launch_bounds__(256) void k_init(
    const float* __restrict__ W, unsigned short* __restrict__ wb,
    int* __restrict__ bucket_cnt, int nbuk, int* __restrict__ over_cnt)
{
    if (blockIdx.x < 32) {
        const int t = blockIdx.x * 256 + threadIdx.x;   // 0..8191
        const int lane = t & 63;
        const int ct = (t >> 6) & 15;
        const int ks = t >> 10;
        const int col = ct * 16 + (lane & 15);
        const int krow = ks * 32 + (lane >> 4) * 8;
#pragma unroll
        for (int j = 0; j < 8; ++j)
            wb[(size_t)t * 8 + j] = f2bf(W[(krow + j) * 256 + col]);
    } else {
        for (int i = threadIdx.x; i < nbuk; i += 256) bucket_cnt[i] = 0;
        if (threadIdx.x == 0) *over_cnt = 0;
    }
}

// ---------------------------------------------------------------------------
// K1: FUSED gemm || bucket.
//   blocks [0, gblocks): ft = feat @ W, software-pipelined, biased-uint8.
//   blocks [gblocks, ...): edge binning, 2048 edges/block, edges in regs.
//     bucket_edges packed 4B: (src<<7) | (dst & 127).
// ---------------------------------------------------------------------------
__global__ __launch_bounds__(256, 4) void k_fused(
    const float* __restrict__ A, const unsigned short* __restrict__ wb,
    const float* __restrict__ attn_l, const float* __restrict__ attn_r,
    unsigned char* __restrict__ qft, float* __restrict__ pk,
    float* __restrict__ ers, int M,
    const int* __restrict__ src, const int* __restrict__ dst, int E, int nbuk,
    int* __restrict__ bucket_cnt, unsigned int* __restrict__ bucket_edges,
    int* __restrict__ over_cnt, int2* __restrict__ over_edges, int gblocks)
{
    __shared__ unsigned char lds_raw[32768];
    const int tid = threadIdx.x;

    if ((int)blockIdx.x >= gblocks) {
        // ---------------- bucket path ----------------
        int* lhist = (int*)lds_raw;            // [MAX_NBUK]
        int* lbase = lhist + MAX_NBUK;
        int* lcur  = lhist + 2 * MAX_NBUK;
        for (int i = tid; i < nbuk; i += 256) lhist[i] = 0;
        __syncthreads();

        const int e0 = ((int)blockIdx.x - gblocks) * 2048;
        int es[8], ed[8];
#pragma unroll
        for (int p = 0; p < 8; ++p) {
            int e = e0 + p * 256 + tid;
            if (e < E) { es[p] = src[e]; ed[p] = dst[e]; }
            else ed[p] = -1;
        }
#pragma unroll
        for (int p = 0; p < 8; ++p)
            if (ed[p] >= 0) atomicAdd(&lhist[ed[p] >> BUK_SHIFT], 1);
        __syncthreads();
        for (int i = tid; i < nbuk; i += 256) {
            int cc = lhist[i];
            lbase[i] = (cc > 0) ? atomicAdd(&bucket_cnt[i], cc) : 0;
            lcur[i] = 0;
        }
        __syncthreads();
#pragma unroll
        for (int p = 0; p < 8; ++p) {
            if (ed[p] >= 0) {
                int bin = ed[p] >> BUK_SHIFT;
                int r = atomicAdd(&lcur[bin], 1);
                int pos = lbase[bin] + r;
                if (pos < BUK_CAP) {
                    bucket_edges[(size_t)bin * BUK_CAP + pos] =
                        ((unsigned int)es[p] << BUK_SHIFT) |
                        (unsigned int)(ed[p] & (BUK_NODES - 1));
                } else {
                    int oi = atomicAdd(over_cnt, 1);
                    if (oi < OVER_CAP) over_edges[oi] = make_int2(es[p], ed[p]);
                }
            }
        }
        return;
    }

    // ---------------- gemm path ----------------
    unsigned short (*bst)[8192] = (unsigned short(*)[8192])lds_raw;   // 2x16KB
    const int w = tid >> 6, lane = tid & 63;
    const int row0 = blockIdx.x * 64 + w * 16;
    const int arow = row0 + (lane & 15);
    const bool aval = arow < M;
    const float* ap = A + (size_t)arow * 256 + (lane >> 4) * 8;
    const uint4* bsrc = (const uint4*)wb;       // 1024 uint4-units per slice

    float4v acc[16];
#pragma unroll
    for (int ct = 0; ct < 16; ++ct) acc[ct] = (float4v){0.f, 0.f, 0.f, 0.f};

    uint4 breg0, breg1, breg2, breg3;
    breg0 = bsrc[0 * 256 + tid];
    breg1 = bsrc[1 * 256 + tid];
    breg2 = bsrc[2 * 256 + tid];
    breg3 = bsrc[3 * 256 + tid];
    float4 a0 = make_float4(0.f, 0.f, 0.f, 0.f), a1 = a0;
    if (aval) { a0 = *(const float4*)ap; a1 = *(const float4*)(ap + 4); }
    {
        uint4* d = (uint4*)bst[0];
        d[0 * 256 + tid] = breg0;
        d[1 * 256 + tid] = breg1;
        d[2 * 256 + tid] = breg2;
        d[3 * 256 + tid] = breg3;
    }
    __syncthreads();

    for (int ks = 0; ks < 8; ++ks) {
        const int cur = ks & 1;
        float4 na0 = make_float4(0.f, 0.f, 0.f, 0.f), na1 = na0;
        if (ks < 7) {   // issue next-slice loads early
            const int u0 = (ks + 1) * 1024 + tid;
            breg0 = bsrc[u0];
            breg1 = bsrc[u0 + 256];
            breg2 = bsrc[u0 + 512];
            breg3 = bsrc[u0 + 768];
            if (aval) {
                na0 = *(const float4*)(ap + (ks + 1) * 32);
                na1 = *(const float4*)(ap + (ks + 1) * 32 + 4);
            }
        }
        short8v ahi, alo;
        {
            float av[8] = {a0.x, a0.y, a0.z, a0.w, a1.x, a1.y, a1.z, a1.w};
#pragma unroll
            for (int j = 0; j < 8; ++j) {
                unsigned short h = f2bf(av[j]);
                ahi[j] = (short)h;
                alo[j] = (short)f2bf(av[j] - bf2f(h));
            }
        }
#pragma unroll
        for (int ct = 0; ct < 16; ++ct) {
            short8v b = *(const short8v*)(&bst[cur][ct * 512 + lane * 8]);
            acc[ct] = __builtin_amdgcn_mfma_f32_16x16x32_bf16(ahi, b, acc[ct], 0, 0, 0);
            acc[ct] = __builtin_amdgcn_mfma_f32_16x16x32_bf16(alo, b, acc[ct], 0, 0, 0);
        }
        if (ks < 7) {
            uint4* d = (uint4*)bst[cur ^ 1];
            d[0 * 256 + tid] = breg0;
            d[1 * 256 + tid] = breg1;
            d[2 * 256 + tid] = breg2;
            d[3 * 256 + tid] = breg3;
            a0 = na0; a1 = na1;
        }
        __syncthreads();
    }

    unsigned char* smq = lds_raw + (size_t)w * 4224;   // [16][264]
    const int c = lane & 15, g = lane >> 4;

#pragma unroll
    for (int reg = 0; reg < 4; ++reg) {
        const int row = row0 + g * 4 + reg;
#pragma unroll
        for (int h = 0; h < 8; ++h) {
            float v0 = acc[2 * h][reg], v1 = acc[2 * h + 1][reg];
            float pl = v0 * attn_l[h * 32 + c] + v1 * attn_l[h * 32 + 16 + c];
            float pr = v0 * attn_r[h * 32 + c] + v1 * attn_r[h * 32 + 16 + c];
            float mx = fmaxf(fabsf(v0), fabsf(v1));
#pragma unroll
            for (int off = 1; off <= 8; off <<= 1) {
                pl += __shfl_xor(pl, off);
                pr += __shfl_xor(pr, off);
                mx = fmaxf(mx, __shfl_xor(mx, off));
            }
            float inv = mx > 0.f ? 127.f / mx : 0.f;
            int q0 = (int)rintf(v0 * inv) + 128;
            int q1 = (int)rintf(v1 * inv) + 128;
            smq[(g * 4 + reg) * 264 + h * 32 + c]      = (unsigned char)q0;
            smq[(g * 4 + reg) * 264 + h * 32 + 16 + c] = (unsigned char)q1;
            if (c == 0 && row < M) {
                pk[(row * 8 + h) * 2]     = pl * LOG2E;
                pk[(row * 8 + h) * 2 + 1] = mx * (1.f / 127.f);
                ers[row * 8 + h]          = pr * LOG2E;
            }
        }
    }
    __syncthreads();
#pragma unroll
    for (int it = 0; it < 16; ++it) {
        int grow = row0 + it;
        if (grow < M)
            *(unsigned int*)(qft + (size_t)grow * 256 + lane * 4) =
                *(const unsigned int*)(smq + it * 264 + lane * 4);
    }
}

// ---------------------------------------------------------------------------
// K3: per-bucket CSR finalize — packed edges read ONCE into registers.
// ---------------------------------------------------------------------------
__global__ __launch_bounds__(256) void k_csr(
    const unsigned int* __restrict__ bucket_edges, const int* __restrict__ bucket_cnt,
    int N, int* __restrict__ deg, int* __restrict__ row_start,
    int* __restrict__ perm_src)
{
    __shared__ int hist[BUK_NODES];
    __shared__ int pfx[BUK_NODES];
    __shared__ int curs[BUK_NODES];
    const int bu = blockIdx.x;
    const int tid = threadIdx.x;
    const int cnt = min(bucket_cnt[bu], BUK_CAP);
    const int node0 = bu << BUK_SHIFT;
    if (tid < BUK_NODES) hist[tid] = 0;
    __syncthreads();

    unsigned int er[CSR_MAXR];
#pragma unroll
    for (int r = 0; r < CSR_MAXR; ++r) {
        int i = tid + r * 256;
        er[r] = (i < cnt) ? bucket_edges[(size_t)bu * BUK_CAP + i] : 0xFFFFFFFFu;
    }
#pragma unroll
    for (int r = 0; r < CSR_MAXR; ++r)
        if (er[r] != 0xFFFFFFFFu)
            atomicAdd(&hist[er[r] & (BUK_NODES - 1)], 1);
    __syncthreads();
    if (tid == 0) {
        int s = 0;
#pragma unroll
        for (int i = 0; i < BUK_NODES; ++i) { pfx[i] = s; s += hist[i]; }
    }
    __syncthreads();
    if (tid < BUK_NODES) {
        int n = node0 + tid;
        if (n < N) {
            deg[n] = hist[tid];
            row_start[n] = bu * BUK_CAP + pfx[tid];
        }
        curs[tid] = pfx[tid];
    }
    __syncthreads();
#pragma unroll
    for (int r = 0; r < CSR_MAXR; ++r) {
        if (er[r] != 0xFFFFFFFFu) {
            int p = atomicAdd(&curs[er[r] & (BUK_NODES - 1)], 1);
            perm_src[(size_t)bu * BUK_CAP + p] = (int)(er[r] >> BUK_SHIFT);
        }
    }
}

// ---------------------------------------------------------------------------
// K4: per-dst aggregation, 8-edge blocks, biased-uint8 ft. Streams kept out
// of L2: perm_src via nontemporal load, out via nontemporal store — frees
// L2 capacity for the reused qft/pk gather data.
// ---------------------------------------------------------------------------
__global__ __launch_bounds__(256) void k_agg(
    const unsigned char* __restrict__ qft,
    const float* __restrict__ pk, const float* __restrict__ ers,
    const int* __restrict__ row_start, const int* __restrict__ deg,
    const int* __restrict__ perm_src,
    const float* __restrict__ bias, float* __restrict__ out, int N,
    const int* __restrict__ over_cnt, const int2* __restrict__ over_edges)
{
    const int tid = threadIdx.x;
    const int lane = tid & 63;
    const int n = blockIdx.x * 4 + (tid >> 6);
    if (n >= N) return;
    const int h = lane >> 3;
    const int slot = lane & 7;
    const int grp = lane & 56;
    const int colb = lane * 4;
    const float erh = ers[(size_t)n * 8 + h];
    const int start = row_start[n];
    const int cnt = deg[n];

    float a0 = 0.f, a1 = 0.f, a2 = 0.f, a3 = 0.f;
    float swb = 0.f, swsb = 0.f;    // raw / scaled partials (own slots)
    float swt = 0.f, swst = 0.f;    // tail raw / scaled (replicated)

    const int nblk = cnt & ~7;
    int j = 0;
    int s_mine = 0;
    if (nblk > 0) s_mine = __builtin_nontemporal_load(&perm_src[start + slot]);
    while (j < nblk) {
        const int s_cur = s_mine;
        j += 8;
        if (j < nblk) s_mine = __builtin_nontemporal_load(&perm_src[start + j + slot]);
        float2 g = *(const float2*)&pk[((size_t)s_cur * 8 + h) * 2];
        float t = g.x + erh;
        t = fmaxf(t, NEG_SLOPE * t);
        float wraw = __builtin_amdgcn_exp2f(t);
        float wsc = wraw * g.y;
        swb += wraw;
        swsb += wsc;
        const int soff = s_cur << 8;
#pragma unroll
        for (int k = 0; k < 8; ++k) {
            int ok = __shfl(soff, grp | k);
            float wk = __shfl(wsc, grp | k);
            unsigned int d = *(const unsigned int*)&qft[(size_t)(ok + colb)];
            a0 = fmaf(wk, ub2f(d, 0), a0);
            a1 = fmaf(wk, ub2f(d, 1), a1);
            a2 = fmaf(wk, ub2f(d, 2), a2);
            a3 = fmaf(wk, ub2f(d, 3), a3);
        }
    }
    for (; j < cnt; ++j) {
        int sv = __builtin_nontemporal_load(&perm_src[start + j]);
        float2 g = *(const float2*)&pk[((size_t)sv * 8 + h) * 2];
        float t = g.x + erh;
        t = fmaxf(t, NEG_SLOPE * t);
        float wraw = __builtin_amdgcn_exp2f(t);
        float wsc = wraw * g.y;
        swt += wraw;
        swst += wsc;
        unsigned int d = *(const unsigned int*)&qft[(size_t)sv * 256 + colb];
        a0 = fmaf(wsc, ub2f(d, 0), a0);
        a1 = fmaf(wsc, ub2f(d, 1), a1);
        a2 = fmaf(wsc, ub2f(d, 2), a2);
        a3 = fmaf(wsc, ub2f(d, 3), a3);
    }

    swb  += __shfl_xor(swb, 1);
    swsb += __shfl_xor(swsb, 1);
    swb  += __shfl_xor(swb, 2);
    swsb += __shfl_xor(swsb, 2);
    swb  += __shfl_xor(swb, 4);
    swsb += __shfl_xor(swsb, 4);
    float swv = swb + swt;
    float sws = swsb + swst;

    int oc = *over_cnt;
    if (oc > 0) {
        oc = min(oc, OVER_CAP);
        for (int i = 0; i < oc; ++i) {
            int2 ed = over_edges[i];
            if (ed.y == n) {
                float2 g = *(const float2*)&pk[((size_t)ed.x * 8 + h) * 2];
                float e = g.x + erh;
                e = e > 0.f ? e : NEG_SLOPE * e;
                float wv = __builtin_amdgcn_exp2f(e);
                float wsx = wv * g.y;
                unsigned int d = *(const unsigned int*)&qft[(size_t)ed.x * 256 + colb];
                a0 = fmaf(wsx, ub2f(d, 0), a0);
                a1 = fmaf(wsx, ub2f(d, 1), a1);
                a2 = fmaf(wsx, ub2f(d, 2), a2);
                a3 = fmaf(wsx, ub2f(d, 3), a3);
                swv += wv;
                sws += wsx;
            }
        }
    }

    float corr = 128.f * sws;
    float inv = swv != 0.f ? 1.f / swv : 0.f;
    float4 b = *(const float4*)&bias[colb];
    float4v o;
    o[0] = (a0 - corr) * inv + b.x;
    o[1] = (a1 - corr) * inv + b.y;
    o[2] = (a2 - corr) * inv + b.z;
    o[3] = (a3 - corr) * inv + b.w;
    __builtin_nontemporal_store(o, (float4v*)&out[(size_t)n * 256 + colb]);
}

// ---------------------------------------------------------------------------
extern "C" void kernel_launch(void* const* d_in, const int* in_sizes, int n_in,
                              void* d_out, int out_size, void* d_ws, size_t ws_size,
                              hipStream_t stream)
{
    const float* feat   = (const float*)d_in[0];
    const float* W      = (const float*)d_in[1];
    const float* attn_l = (const float*)d_in[2];
    const float* attn_r = (const float*)d_in[3];
    const float* bias   = (const float*)d_in[4];
    const int*   src    = (const int*)d_in[5];
    const int*   dst    = (const int*)d_in[6];
    const int N = in_sizes[0] / 256;
    const int E = in_sizes[5];
    const int nbuk = (N + BUK_NODES - 1) >> BUK_SHIFT;
    float* out = (float*)d_out;

    char* ws = (char*)d_ws;
    size_t off = 0;
    auto wsalloc = [&](size_t bytes) -> char* {
        char* p = ws + off;
        off = (off + bytes + 255) & ~(size_t)255;
        return p;
    };
    unsigned char* qft   = (unsigned char*)wsalloc((size_t)N * 256);            // 12.8 MB
    float* pk            = (float*)wsalloc((size_t)N * 16 * 4);                 // 3.2 MB (el,scale)
    float* ers           = (float*)wsalloc((size_t)N * 8 * 4);                  // 1.6 MB
    int* deg             = (int*)wsalloc((size_t)N * 4);
    int* row_start       = (int*)wsalloc((size_t)N * 4);
    int* bucket_cnt      = (int*)wsalloc((size_t)nbuk * 4);
    unsigned int* bucket_edges = (unsigned int*)wsalloc((size_t)nbuk * BUK_CAP * 4); // 8 MB
    int* perm_src        = (int*)wsalloc((size_t)nbuk * BUK_CAP * 4);           // 8 MB
    int* over_cnt        = (int*)wsalloc(256);
    int2* over_edges     = (int2*)wsalloc((size_t)OVER_CAP * 8);
    unsigned short* wb   = (unsigned short*)wsalloc((size_t)65536 * 2);         // 128 KB
    (void)ws_size; (void)n_in; (void)out_size;

    const int gblocks = (N + 63) / 64;
    const int bblocks = (E + 2047) / 2048;

    k_init<<<33, 256, 0, stream>>>(W, wb, bucket_cnt, nbuk, over_cnt);
    k_fused<<<gblocks + bblocks, 256, 0, stream>>>(feat, wb, attn_l, attn_r,
        qft, pk, ers, N, src, dst, E, nbuk,
        bucket_cnt, bucket_edges, over_cnt, over_edges, gblocks);
    k_csr<<<nbuk, 256, 0, stream>>>(bucket_edges, bucket_cnt, N, deg, row_start, perm_src);
    k_agg<<<(N + 3) / 4, 256, 0, stream>>>(qft, pk, ers, row_start, deg, perm_src,
        bias, out, N, over_cnt, over_edges);
}

// Round 14
// 140.234 us; speedup vs baseline: 1.0258x; 1.0258x over previous
//
#include <hip/hip_runtime.h>

#define NEG_SLOPE 0.2f
#define LOG2E 1.44269504088896340736f

#define BUK_SHIFT 7
#define BUK_NODES 128
#define BUK_CAP   5120
#define MAX_NBUK  512
#define OVER_CAP  4096
#define CSR_MAXR  20        // ceil(BUK_CAP/256)

typedef __attribute__((ext_vector_type(8))) short short8v;
typedef __attribute__((ext_vector_type(4))) float float4v;

__device__ __forceinline__ float bf2f(unsigned short u) {
    union { unsigned int u32; float f; } c;
    c.u32 = ((unsigned int)u) << 16;
    return c.f;
}
__device__ __forceinline__ unsigned short f2bf(float f) {
    union { float f; unsigned int u32; } c; c.f = f;
    unsigned int b = c.u32;
    b += 0x7fffu + ((b >> 16) & 1u);   // round-to-nearest-even
    return (unsigned short)(b >> 16);
}
// unsigned byte b of dword d -> float (v_cvt_f32_ubyteN, 1 instr)
__device__ __forceinline__ float ub2f(unsigned int d, int b) {
    return (float)((d >> (8 * b)) & 0xffu);
}

// ---------------------------------------------------------------------------
// K0: fused init. Blocks 0..31: W -> bf16 in MFMA B-fragment order.
// Block 32: zero bucket counters + overflow counter.
// ---------------------------------------------------------------------------
__global__ __launch_bounds__(256) void k_init(
    const float* __restrict__ W, unsigned short* __restrict__ wb,
    int* __restrict__ bucket_cnt, int nbuk, int* __restrict__ over_cnt)
{
    if (blockIdx.x < 32) {
        const int t = blockIdx.x * 256 + threadIdx.x;   // 0..8191
        const int lane = t & 63;
        const int ct = (t >> 6) & 15;
        const int ks = t >> 10;
        const int col = ct * 16 + (lane & 15);
        const int krow = ks * 32 + (lane >> 4) * 8;
#pragma unroll
        for (int j = 0; j < 8; ++j)
            wb[(size_t)t * 8 + j] = f2bf(W[(krow + j) * 256 + col]);
    } else {
        for (int i = threadIdx.x; i < nbuk; i += 256) bucket_cnt[i] = 0;
        if (threadIdx.x == 0) *over_cnt = 0;
    }
}

// ---------------------------------------------------------------------------
// K1: FUSED gemm || bucket.
//   blocks [0, gblocks): ft = feat @ W, software-pipelined, biased-uint8.
//   blocks [gblocks, ...): edge binning, 2048 edges/block, edges in regs.
//     bucket_edges packed 4B: (src<<7) | (dst & 127).
// ---------------------------------------------------------------------------
__global__ __launch_bounds__(256, 4) void k_fused(
    const float* __restrict__ A, const unsigned short* __restrict__ wb,
    const float* __restrict__ attn_l, const float* __restrict__ attn_r,
    unsigned char* __restrict__ qft, float* __restrict__ pk,
    float* __restrict__ ers, int M,
    const int* __restrict__ src, const int* __restrict__ dst, int E, int nbuk,
    int* __restrict__ bucket_cnt, unsigned int* __restrict__ bucket_edges,
    int* __restrict__ over_cnt, int2* __restrict__ over_edges, int gblocks)
{
    __shared__ unsigned char lds_raw[32768];
    const int tid = threadIdx.x;

    if ((int)blockIdx.x >= gblocks) {
        // ---------------- bucket path ----------------
        int* lhist = (int*)lds_raw;            // [MAX_NBUK]
        int* lbase = lhist + MAX_NBUK;
        int* lcur  = lhist + 2 * MAX_NBUK;
        for (int i = tid; i < nbuk; i += 256) lhist[i] = 0;
        __syncthreads();

        const int e0 = ((int)blockIdx.x - gblocks) * 2048;
        int es[8], ed[8];
#pragma unroll
        for (int p = 0; p < 8; ++p) {
            int e = e0 + p * 256 + tid;
            if (e < E) { es[p] = src[e]; ed[p] = dst[e]; }
            else ed[p] = -1;
        }
#pragma unroll
        for (int p = 0; p < 8; ++p)
            if (ed[p] >= 0) atomicAdd(&lhist[ed[p] >> BUK_SHIFT], 1);
        __syncthreads();
        for (int i = tid; i < nbuk; i += 256) {
            int cc = lhist[i];
            lbase[i] = (cc > 0) ? atomicAdd(&bucket_cnt[i], cc) : 0;
            lcur[i] = 0;
        }
        __syncthreads();
#pragma unroll
        for (int p = 0; p < 8; ++p) {
            if (ed[p] >= 0) {
                int bin = ed[p] >> BUK_SHIFT;
                int r = atomicAdd(&lcur[bin], 1);
                int pos = lbase[bin] + r;
                if (pos < BUK_CAP) {
                    bucket_edges[(size_t)bin * BUK_CAP + pos] =
                        ((unsigned int)es[p] << BUK_SHIFT) |
                        (unsigned int)(ed[p] & (BUK_NODES - 1));
                } else {
                    int oi = atomicAdd(over_cnt, 1);
                    if (oi < OVER_CAP) over_edges[oi] = make_int2(es[p], ed[p]);
                }
            }
        }
        return;
    }

    // ---------------- gemm path ----------------
    unsigned short (*bst)[8192] = (unsigned short(*)[8192])lds_raw;   // 2x16KB
    const int w = tid >> 6, lane = tid & 63;
    const int row0 = blockIdx.x * 64 + w * 16;
    const int arow = row0 + (lane & 15);
    const bool aval = arow < M;
    const float* ap = A + (size_t)arow * 256 + (lane >> 4) * 8;
    const uint4* bsrc = (const uint4*)wb;       // 1024 uint4-units per slice

    float4v acc[16];
#pragma unroll
    for (int ct = 0; ct < 16; ++ct) acc[ct] = (float4v){0.f, 0.f, 0.f, 0.f};

    uint4 breg0, breg1, breg2, breg3;
    breg0 = bsrc[0 * 256 + tid];
    breg1 = bsrc[1 * 256 + tid];
    breg2 = bsrc[2 * 256 + tid];
    breg3 = bsrc[3 * 256 + tid];
    float4 a0 = make_float4(0.f, 0.f, 0.f, 0.f), a1 = a0;
    if (aval) { a0 = *(const float4*)ap; a1 = *(const float4*)(ap + 4); }
    {
        uint4* d = (uint4*)bst[0];
        d[0 * 256 + tid] = breg0;
        d[1 * 256 + tid] = breg1;
        d[2 * 256 + tid] = breg2;
        d[3 * 256 + tid] = breg3;
    }
    __syncthreads();

    for (int ks = 0; ks < 8; ++ks) {
        const int cur = ks & 1;
        float4 na0 = make_float4(0.f, 0.f, 0.f, 0.f), na1 = na0;
        if (ks < 7) {   // issue next-slice loads early
            const int u0 = (ks + 1) * 1024 + tid;
            breg0 = bsrc[u0];
            breg1 = bsrc[u0 + 256];
            breg2 = bsrc[u0 + 512];
            breg3 = bsrc[u0 + 768];
            if (aval) {
                na0 = *(const float4*)(ap + (ks + 1) * 32);
                na1 = *(const float4*)(ap + (ks + 1) * 32 + 4);
            }
        }
        short8v ahi, alo;
        {
            float av[8] = {a0.x, a0.y, a0.z, a0.w, a1.x, a1.y, a1.z, a1.w};
#pragma unroll
            for (int j = 0; j < 8; ++j) {
                unsigned short h = f2bf(av[j]);
                ahi[j] = (short)h;
                alo[j] = (short)f2bf(av[j] - bf2f(h));
            }
        }
#pragma unroll
        for (int ct = 0; ct < 16; ++ct) {
            short8v b = *(const short8v*)(&bst[cur][ct * 512 + lane * 8]);
            acc[ct] = __builtin_amdgcn_mfma_f32_16x16x32_bf16(ahi, b, acc[ct], 0, 0, 0);
            acc[ct] = __builtin_amdgcn_mfma_f32_16x16x32_bf16(alo, b, acc[ct], 0, 0, 0);
        }
        if (ks < 7) {
            uint4* d = (uint4*)bst[cur ^ 1];
            d[0 * 256 + tid] = breg0;
            d[1 * 256 + tid] = breg1;
            d[2 * 256 + tid] = breg2;
            d[3 * 256 + tid] = breg3;
            a0 = na0; a1 = na1;
        }
        __syncthreads();
    }

    unsigned char* smq = lds_raw + (size_t)w * 4224;   // [16][264]
    const int c = lane & 15, g = lane >> 4;

#pragma unroll
    for (int reg = 0; reg < 4; ++reg) {
        const int row = row0 + g * 4 + reg;
#pragma unroll
        for (int h = 0; h < 8; ++h) {
            float v0 = acc[2 * h][reg], v1 = acc[2 * h + 1][reg];
            float pl = v0 * attn_l[h * 32 + c] + v1 * attn_l[h * 32 + 16 + c];
            float pr = v0 * attn_r[h * 32 + c] + v1 * attn_r[h * 32 + 16 + c];
            float mx = fmaxf(fabsf(v0), fabsf(v1));
#pragma unroll
            for (int off = 1; off <= 8; off <<= 1) {
                pl += __shfl_xor(pl, off);
                pr += __shfl_xor(pr, off);
                mx = fmaxf(mx, __shfl_xor(mx, off));
            }
            float inv = mx > 0.f ? 127.f / mx : 0.f;
            int q0 = (int)rintf(v0 * inv) + 128;
            int q1 = (int)rintf(v1 * inv) + 128;
            smq[(g * 4 + reg) * 264 + h * 32 + c]      = (unsigned char)q0;
            smq[(g * 4 + reg) * 264 + h * 32 + 16 + c] = (unsigned char)q1;
            if (c == 0 && row < M) {
                pk[(row * 8 + h) * 2]     = pl * LOG2E;
                pk[(row * 8 + h) * 2 + 1] = mx * (1.f / 127.f);
                ers[row * 8 + h]          = pr * LOG2E;
            }
        }
    }
    __syncthreads();
#pragma unroll
    for (int it = 0; it < 16; ++it) {
        int grow = row0 + it;
        if (grow < M)
            *(unsigned int*)(qft + (size_t)grow * 256 + lane * 4) =
                *(const unsigned int*)(smq + it * 264 + lane * 4);
    }
}

// ---------------------------------------------------------------------------
// K3: per-bucket CSR finalize — packed edges read ONCE into registers.
// ---------------------------------------------------------------------------
__global__ __launch_bounds__(256) void k_csr(
    const unsigned int* __restrict__ bucket_edges, const int* __restrict__ bucket_cnt,
    int N, int* __restrict__ deg, int* __restrict__ row_start,
    int* __restrict__ perm_src)
{
    __shared__ int hist[BUK_NODES];
    __shared__ int pfx[BUK_NODES];
    __shared__ int curs[BUK_NODES];
    const int bu = blockIdx.x;
    const int tid = threadIdx.x;
    const int cnt = min(bucket_cnt[bu], BUK_CAP);
    const int node0 = bu << BUK_SHIFT;
    if (tid < BUK_NODES) hist[tid] = 0;
    __syncthreads();

    unsigned int er[CSR_MAXR];
#pragma unroll
    for (int r = 0; r < CSR_MAXR; ++r) {
        int i = tid + r * 256;
        er[r] = (i < cnt) ? bucket_edges[(size_t)bu * BUK_CAP + i] : 0xFFFFFFFFu;
    }
#pragma unroll
    for (int r = 0; r < CSR_MAXR; ++r)
        if (er[r] != 0xFFFFFFFFu)
            atomicAdd(&hist[er[r] & (BUK_NODES - 1)], 1);
    __syncthreads();
    if (tid == 0) {
        int s = 0;
#pragma unroll
        for (int i = 0; i < BUK_NODES; ++i) { pfx[i] = s; s += hist[i]; }
    }
    __syncthreads();
    if (tid < BUK_NODES) {
        int n = node0 + tid;
        if (n < N) {
            deg[n] = hist[tid];
            row_start[n] = bu * BUK_CAP + pfx[tid];
        }
        curs[tid] = pfx[tid];
    }
    __syncthreads();
#pragma unroll
    for (int r = 0; r < CSR_MAXR; ++r) {
        if (er[r] != 0xFFFFFFFFu) {
            int p = atomicAdd(&curs[er[r] & (BUK_NODES - 1)], 1);
            perm_src[(size_t)bu * BUK_CAP + p] = (int)(er[r] >> BUK_SHIFT);
        }
    }
}

// ---------------------------------------------------------------------------
// K4: per-dst aggregation, 8-edge blocks, biased-uint8 ft (best measured
// form, R12: plain cached loads/stores — NT hints regressed).
// ---------------------------------------------------------------------------
__global__ __launch_bounds__(256) void k_agg(
    const unsigned char* __restrict__ qft,
    const float* __restrict__ pk, const float* __restrict__ ers,
    const int* __restrict__ row_start, const int* __restrict__ deg,
    const int* __restrict__ perm_src,
    const float* __restrict__ bias, float* __restrict__ out, int N,
    const int* __restrict__ over_cnt, const int2* __restrict__ over_edges)
{
    const int tid = threadIdx.x;
    const int lane = tid & 63;
    const int n = blockIdx.x * 4 + (tid >> 6);
    if (n >= N) return;
    const int h = lane >> 3;
    const int slot = lane & 7;
    const int grp = lane & 56;
    const int colb = lane * 4;
    const float erh = ers[(size_t)n * 8 + h];
    const int start = row_start[n];
    const int cnt = deg[n];

    float a0 = 0.f, a1 = 0.f, a2 = 0.f, a3 = 0.f;
    float swb = 0.f, swsb = 0.f;    // raw / scaled partials (own slots)
    float swt = 0.f, swst = 0.f;    // tail raw / scaled (replicated)

    const int nblk = cnt & ~7;
    int j = 0;
    int s_mine = 0;
    if (nblk > 0) s_mine = perm_src[start + slot];
    while (j < nblk) {
        const int s_cur = s_mine;
        j += 8;
        if (j < nblk) s_mine = perm_src[start + j + slot];
        float2 g = *(const float2*)&pk[((size_t)s_cur * 8 + h) * 2];
        float t = g.x + erh;
        t = fmaxf(t, NEG_SLOPE * t);
        float wraw = __builtin_amdgcn_exp2f(t);
        float wsc = wraw * g.y;
        swb += wraw;
        swsb += wsc;
        const int soff = s_cur << 8;
#pragma unroll
        for (int k = 0; k < 8; ++k) {
            int ok = __shfl(soff, grp | k);
            float wk = __shfl(wsc, grp | k);
            unsigned int d = *(const unsigned int*)&qft[(size_t)(ok + colb)];
            a0 = fmaf(wk, ub2f(d, 0), a0);
            a1 = fmaf(wk, ub2f(d, 1), a1);
            a2 = fmaf(wk, ub2f(d, 2), a2);
            a3 = fmaf(wk, ub2f(d, 3), a3);
        }
    }
    for (; j < cnt; ++j) {
        int sv = perm_src[start + j];
        float2 g = *(const float2*)&pk[((size_t)sv * 8 + h) * 2];
        float t = g.x + erh;
        t = fmaxf(t, NEG_SLOPE * t);
        float wraw = __builtin_amdgcn_exp2f(t);
        float wsc = wraw * g.y;
        swt += wraw;
        swst += wsc;
        unsigned int d = *(const unsigned int*)&qft[(size_t)sv * 256 + colb];
        a0 = fmaf(wsc, ub2f(d, 0), a0);
        a1 = fmaf(wsc, ub2f(d, 1), a1);
        a2 = fmaf(wsc, ub2f(d, 2), a2);
        a3 = fmaf(wsc, ub2f(d, 3), a3);
    }

    swb  += __shfl_xor(swb, 1);
    swsb += __shfl_xor(swsb, 1);
    swb  += __shfl_xor(swb, 2);
    swsb += __shfl_xor(swsb, 2);
    swb  += __shfl_xor(swb, 4);
    swsb += __shfl_xor(swsb, 4);
    float swv = swb + swt;
    float sws = swsb + swst;

    int oc = *over_cnt;
    if (oc > 0) {
        oc = min(oc, OVER_CAP);
        for (int i = 0; i < oc; ++i) {
            int2 ed = over_edges[i];
            if (ed.y == n) {
                float2 g = *(const float2*)&pk[((size_t)ed.x * 8 + h) * 2];
                float e = g.x + erh;
                e = e > 0.f ? e : NEG_SLOPE * e;
                float wv = __builtin_amdgcn_exp2f(e);
                float wsx = wv * g.y;
                unsigned int d = *(const unsigned int*)&qft[(size_t)ed.x * 256 + colb];
                a0 = fmaf(wsx, ub2f(d, 0), a0);
                a1 = fmaf(wsx, ub2f(d, 1), a1);
                a2 = fmaf(wsx, ub2f(d, 2), a2);
                a3 = fmaf(wsx, ub2f(d, 3), a3);
                swv += wv;
                sws += wsx;
            }
        }
    }

    float corr = 128.f * sws;
    float inv = swv != 0.f ? 1.f / swv : 0.f;
    float4 b = *(const float4*)&bias[colb];
    float4 o;
    o.x = (a0 - corr) * inv + b.x;
    o.y = (a1 - corr) * inv + b.y;
    o.z = (a2 - corr) * inv + b.z;
    o.w = (a3 - corr) * inv + b.w;
    *(float4*)&out[(size_t)n * 256 + colb] = o;
}

// ---------------------------------------------------------------------------
extern "C" void kernel_launch(void* const* d_in, const int* in_sizes, int n_in,
                              void* d_out, int out_size, void* d_ws, size_t ws_size,
                              hipStream_t stream)
{
    const float* feat   = (const float*)d_in[0];
    const float* W      = (const float*)d_in[1];
    const float* attn_l = (const float*)d_in[2];
    const float* attn_r = (const float*)d_in[3];
    const float* bias   = (const float*)d_in[4];
    const int*   src    = (const int*)d_in[5];
    const int*   dst    = (const int*)d_in[6];
    const int N = in_sizes[0] / 256;
    const int E = in_sizes[5];
    const int nbuk = (N + BUK_NODES - 1) >> BUK_SHIFT;
    float* out = (float*)d_out;

    char* ws = (char*)d_ws;
    size_t off = 0;
    auto wsalloc = [&](size_t bytes) -> char* {
        char* p = ws + off;
        off = (off + bytes + 255) & ~(size_t)255;
        return p;
    };
    unsigned char* qft   = (unsigned char*)wsalloc((size_t)N * 256);            // 12.8 MB
    float* pk            = (float*)wsalloc((size_t)N * 16 * 4);                 // 3.2 MB (el,scale)
    float* ers           = (float*)wsalloc((size_t)N * 8 * 4);                  // 1.6 MB
    int* deg             = (int*)wsalloc((size_t)N * 4);
    int* row_start       = (int*)wsalloc((size_t)N * 4);
    int* bucket_cnt      = (int*)wsalloc((size_t)nbuk * 4);
    unsigned int* bucket_edges = (unsigned int*)wsalloc((size_t)nbuk * BUK_CAP * 4); // 8 MB
    int* perm_src        = (int*)wsalloc((size_t)nbuk * BUK_CAP * 4);           // 8 MB
    int* over_cnt        = (int*)wsalloc(256);
    int2* over_edges     = (int2*)wsalloc((size_t)OVER_CAP * 8);
    unsigned short* wb   = (unsigned short*)wsalloc((size_t)65536 * 2);         // 128 KB
    (void)ws_size; (void)n_in; (void)out_size;

    const int gblocks = (N + 63) / 64;
    const int bblocks = (E + 2047) / 2048;

    k_init<<<33, 256, 0, stream>>>(W, wb, bucket_cnt, nbuk, over_cnt);
    k_fused<<<gblocks + bblocks, 256, 0, stream>>>(feat, wb, attn_l, attn_r,
        qft, pk, ers, N, src, dst, E, nbuk,
        bucket_cnt, bucket_edges, over_cnt, over_edges, gblocks);
    k_csr<<<nbuk, 256, 0, stream>>>(bucket_edges, bucket_cnt, N, deg, row_start, perm_src);
    k_agg<<<(N + 3) / 4, 256, 0, stream>>>(qft, pk, ers, row_start, deg, perm_src,
        bias, out, N, over_cnt, over_edges);
}